// Round 1
// baseline (2763.658 us; speedup 1.0000x reference)
//
#include <hip/hip_runtime.h>

// GCN autoencoder, fp32 throughout.
// Structure per layer: mm = h_in @ W  (wave-per-node, W in LDS)
//                      agg[dst] += mm[src]*dinv[src]*dinv[dst]   (atomic, edges only)
//                      out = agg + mm*dinv^2 (self loop) + b  [, relu]  (in place)

static inline size_t align256(size_t x) { return (x + 255) & ~(size_t)255; }

__global__ void deg_kernel(const int* __restrict__ dst, int E, float* __restrict__ deg) {
    int e = blockIdx.x * blockDim.x + threadIdx.x;
    if (e < E) atomicAdd(&deg[dst[e]], 1.0f);
}

__global__ void dinv_kernel(float* __restrict__ deg, int n) {
    int i = blockIdx.x * blockDim.x + threadIdx.x;
    if (i < n) deg[i] = rsqrtf(deg[i] + 1.0f);   // +1 = self loop; deg >= 1 always
}

// One wave per node. lane l holds x[node][l]; broadcast via shfl; W staged in LDS.
template <int K, int M>
__global__ void matmul_kernel(const float* __restrict__ in, const float* __restrict__ W,
                              float* __restrict__ out, int n) {
    __shared__ float Ws[K * M];
    for (int t = threadIdx.x; t < K * M; t += blockDim.x) Ws[t] = W[t];
    __syncthreads();
    int wave = threadIdx.x >> 6;
    int lane = threadIdx.x & 63;
    int node = blockIdx.x * (blockDim.x >> 6) + wave;
    if (node >= n) return;
    float x = (lane < K) ? in[node * K + lane] : 0.0f;
    int j = lane & (M - 1);
    float acc = 0.0f;
#pragma unroll
    for (int k = 0; k < K; ++k) {
        float w = __shfl(x, k, 64);
        acc = fmaf(w, Ws[k * M + j], acc);
    }
    if (lane < M) out[node * M + lane] = acc;
}

// One thread per (edge, feature). Coalesced gather of mm[src] row, coalesced atomics to agg[dst].
template <int LOGM>
__global__ void agg_kernel(const int* __restrict__ src, const int* __restrict__ dst, int E,
                           const float* __restrict__ dinv, const float* __restrict__ mm,
                           float* __restrict__ agg) {
    const int M = 1 << LOGM;
    int tid = blockIdx.x * blockDim.x + threadIdx.x;
    int e = tid >> LOGM;
    if (e >= E) return;
    int j = tid & (M - 1);
    int s = src[e];
    int d = dst[e];
    float nrm = dinv[s] * dinv[d];
    atomicAdd(&agg[d * M + j], mm[s * M + j] * nrm);
}

// out = agg + mm*dinv^2 + bias [, relu].  out may alias agg (in place).
template <int LOGM, bool RELU>
__global__ void finalize_kernel(const float* __restrict__ aggv, const float* __restrict__ mm,
                                const float* __restrict__ dinv, const float* __restrict__ bias,
                                float* __restrict__ out, int n) {
    const int M = 1 << LOGM;
    int tid = blockIdx.x * blockDim.x + threadIdx.x;
    if (tid >= n * M) return;
    int i = tid >> LOGM;
    int j = tid & (M - 1);
    float di = dinv[i];
    float v = aggv[tid] + mm[tid] * di * di + bias[j];
    if (RELU) v = fmaxf(v, 0.0f);
    out[tid] = v;
}

extern "C" void kernel_launch(void* const* d_in, const int* in_sizes, int n_in,
                              void* d_out, int out_size, void* d_ws, size_t ws_size,
                              hipStream_t stream) {
    (void)n_in; (void)out_size; (void)ws_size;

    const float* x  = (const float*)d_in[0];
    const int*   ei = (const int*)d_in[1];
    const float* W1 = (const float*)d_in[2];  const float* b1 = (const float*)d_in[3];
    const float* W2 = (const float*)d_in[4];  const float* b2 = (const float*)d_in[5];
    const float* W3 = (const float*)d_in[6];  const float* b3 = (const float*)d_in[7];
    const float* W4 = (const float*)d_in[8];  const float* b4 = (const float*)d_in[9];
    const float* W5 = (const float*)d_in[10]; const float* b5 = (const float*)d_in[11];
    const float* W6 = (const float*)d_in[12]; const float* b6 = (const float*)d_in[13];

    const int n = in_sizes[0] / 64;   // 100000
    const int E = in_sizes[1] / 2;    // 1600000
    const int* src = ei;              // edge_index[0]
    const int* dst = ei + E;          // edge_index[1]

    float* out  = (float*)d_out;
    float* xrec = out;                       // [n,64]
    float* z    = out + (size_t)n * 64;      // [n,32]

    char* ws = (char*)d_ws;
    size_t off = 0;
    float* dinv = (float*)(ws + off); off += align256((size_t)n * 4);
    float* buf0 = (float*)(ws + off); off += align256((size_t)n * 64 * 4);  // mm scratch
    float* buf1 = (float*)(ws + off); off += align256((size_t)n * 64 * 4);
    float* buf2 = (float*)(ws + off); off += align256((size_t)n * 64 * 4);

    const int B = 256;
    const int mmGrid  = (n + 3) / 4;                 // 4 waves (nodes) per block
    const int eg64    = (int)(((long long)E * 64 + B - 1) / B);
    const int eg32    = (int)(((long long)E * 32 + B - 1) / B);
    const int fg64    = (int)(((long long)n * 64 + B - 1) / B);
    const int fg32    = (int)(((long long)n * 32 + B - 1) / B);

    // ---- degrees / dinv ----
    hipMemsetAsync(dinv, 0, (size_t)n * 4, stream);
    deg_kernel<<<(E + B - 1) / B, B, 0, stream>>>(dst, E, dinv);
    dinv_kernel<<<(n + B - 1) / B, B, 0, stream>>>(dinv, n);

    // ---- Layer 1: x(64) -> 64, relu -> buf1 ----
    matmul_kernel<64, 64><<<mmGrid, B, 0, stream>>>(x, W1, buf0, n);
    hipMemsetAsync(buf1, 0, (size_t)n * 64 * 4, stream);
    agg_kernel<6><<<eg64, B, 0, stream>>>(src, dst, E, dinv, buf0, buf1);
    finalize_kernel<6, true><<<fg64, B, 0, stream>>>(buf1, buf0, dinv, b1, buf1, n);

    // ---- Layer 2: buf1(64) -> 64, relu -> buf2 ----
    matmul_kernel<64, 64><<<mmGrid, B, 0, stream>>>(buf1, W2, buf0, n);
    hipMemsetAsync(buf2, 0, (size_t)n * 64 * 4, stream);
    agg_kernel<6><<<eg64, B, 0, stream>>>(src, dst, E, dinv, buf0, buf2);
    finalize_kernel<6, true><<<fg64, B, 0, stream>>>(buf2, buf0, dinv, b2, buf2, n);

    // ---- Layer 3: buf2(64) -> 32, NO relu -> z (also output 1) ----
    matmul_kernel<64, 32><<<mmGrid, B, 0, stream>>>(buf2, W3, buf0, n);
    hipMemsetAsync(z, 0, (size_t)n * 32 * 4, stream);
    agg_kernel<5><<<eg32, B, 0, stream>>>(src, dst, E, dinv, buf0, z);
    finalize_kernel<5, false><<<fg32, B, 0, stream>>>(z, buf0, dinv, b3, z, n);

    // ---- Layer 4: z(32) -> 64, relu -> buf1 ----
    matmul_kernel<32, 64><<<mmGrid, B, 0, stream>>>(z, W4, buf0, n);
    hipMemsetAsync(buf1, 0, (size_t)n * 64 * 4, stream);
    agg_kernel<6><<<eg64, B, 0, stream>>>(src, dst, E, dinv, buf0, buf1);
    finalize_kernel<6, true><<<fg64, B, 0, stream>>>(buf1, buf0, dinv, b4, buf1, n);

    // ---- Layer 5: buf1(64) -> 64, relu -> buf2 ----
    matmul_kernel<64, 64><<<mmGrid, B, 0, stream>>>(buf1, W5, buf0, n);
    hipMemsetAsync(buf2, 0, (size_t)n * 64 * 4, stream);
    agg_kernel<6><<<eg64, B, 0, stream>>>(src, dst, E, dinv, buf0, buf2);
    finalize_kernel<6, true><<<fg64, B, 0, stream>>>(buf2, buf0, dinv, b5, buf2, n);

    // ---- Layer 6: buf2(64) -> 64, NO relu -> xrec (output 0) ----
    matmul_kernel<64, 64><<<mmGrid, B, 0, stream>>>(buf2, W6, buf0, n);
    hipMemsetAsync(xrec, 0, (size_t)n * 64 * 4, stream);
    agg_kernel<6><<<eg64, B, 0, stream>>>(src, dst, E, dinv, buf0, xrec);
    finalize_kernel<6, false><<<fg64, B, 0, stream>>>(xrec, buf0, dinv, b6, xrec, n);
}

// Round 2
// 1422.544 us; speedup vs baseline: 1.9428x; 1.9428x over previous
//
#include <hip/hip_runtime.h>

// GCN autoencoder, fp32, CSR gather-based (no float atomics in steady state).
// Per call: build CSR (hist -> scan -> scatter), then 6 fused layers:
//   out[i] = act( (dinv_i^2*in[i] + sum_e w_e*in[src_e]) @ W + b )
// using A(XW) = (AX)W. Layers 3/4 aggregate on the 32-wide side.

static inline size_t align256(size_t x) { return (x + 255) & ~(size_t)255; }

__global__ void hist_kernel(const int* __restrict__ dst, int E, int* __restrict__ cnt) {
    int e = blockIdx.x * blockDim.x + threadIdx.x;
    if (e < E) atomicAdd(&cnt[dst[e]], 1);
}

__global__ void dinv_kernel(const int* __restrict__ cnt, float* __restrict__ dinv, int n) {
    int i = blockIdx.x * blockDim.x + threadIdx.x;
    if (i < n) dinv[i] = rsqrtf((float)cnt[i] + 1.0f);  // +1 self loop
}

// Single-block exclusive scan: row_ptr[0]=0, row_ptr[i+1]=sum(cnt[0..i]).
// 1024 threads, shfl wave-scan + LDS wave-sum scan, sequential carry.
__global__ void scan_kernel(const int* __restrict__ cnt, int* __restrict__ row_ptr, int n) {
    __shared__ int wsum[16];
    __shared__ int carry;
    int tid = threadIdx.x, lane = tid & 63, wv = tid >> 6;
    if (tid == 0) { carry = 0; row_ptr[0] = 0; }
    __syncthreads();
    for (int base = 0; base < n; base += 1024) {
        int idx = base + tid;
        int v = (idx < n) ? cnt[idx] : 0;
        int x = v;
#pragma unroll
        for (int off = 1; off < 64; off <<= 1) {
            int t = __shfl_up(x, off, 64);
            if (lane >= off) x += t;
        }
        if (lane == 63) wsum[wv] = x;
        __syncthreads();
        if (wv == 0 && lane < 16) {
            int s = wsum[lane];
#pragma unroll
            for (int off = 1; off < 16; off <<= 1) {
                int t = __shfl_up(s, off, 16);
                if ((lane & 15) >= off) s += t;
            }
            wsum[lane] = s;  // inclusive scan of wave sums
        }
        __syncthreads();
        int waveoff = (wv == 0) ? 0 : wsum[wv - 1];
        if (idx < n) row_ptr[idx + 1] = carry + waveoff + x;
        __syncthreads();
        if (tid == 0) carry += wsum[15];
        __syncthreads();
    }
}

__global__ void scatter_kernel(const int* __restrict__ src, const int* __restrict__ dst, int E,
                               const int* __restrict__ row_ptr, int* __restrict__ cur,
                               const float* __restrict__ dinv,
                               int* __restrict__ csr_src, float* __restrict__ csr_w) {
    int e = blockIdx.x * blockDim.x + threadIdx.x;
    if (e >= E) return;
    int s = src[e], d = dst[e];
    int pos = row_ptr[d] + atomicAdd(&cur[d], 1);
    csr_src[pos] = s;
    csr_w[pos] = dinv[s] * dinv[d];
}

// Wave-per-node matmul (used only for layer 3 pre-agg shrink 64->32).
template <int K, int M>
__global__ void matmul_kernel(const float* __restrict__ in, const float* __restrict__ W,
                              float* __restrict__ out, int n) {
    __shared__ float Ws[K * M];
    for (int t = threadIdx.x; t < K * M; t += blockDim.x) Ws[t] = W[t];
    __syncthreads();
    int wave = threadIdx.x >> 6, lane = threadIdx.x & 63;
    int node = blockIdx.x * (blockDim.x >> 6) + wave;
    if (node >= n) return;
    float x = (lane < K) ? in[(size_t)node * K + lane] : 0.0f;
    int j = lane & (M - 1);
    float acc = 0.0f;
#pragma unroll
    for (int k = 0; k < K; ++k) acc = fmaf(__shfl(x, k, 64), Ws[k * M + j], acc);
    if (lane < M) out[(size_t)node * M + lane] = acc;
}

// Fused: aggregate (self + CSR neighbors) at width K, then optional @W (K->M), +bias, optional relu.
template <int K, int M, bool RELU, bool HAS_W>
__global__ void fused_layer(const float* __restrict__ in, const float* __restrict__ W,
                            const float* __restrict__ bias,
                            const int* __restrict__ row_ptr, const int* __restrict__ csr_src,
                            const float* __restrict__ csr_w, const float* __restrict__ dinv,
                            float* __restrict__ out, int n) {
    __shared__ float Ws[HAS_W ? K * M : 1];
    if (HAS_W) {
        for (int t = threadIdx.x; t < K * M; t += blockDim.x) Ws[t] = W[t];
        __syncthreads();
    }
    int wave = threadIdx.x >> 6, lane = threadIdx.x & 63;
    int i = blockIdx.x * (blockDim.x >> 6) + wave;
    if (i >= n) return;
    float di = dinv[i];
    float acc = (lane < K) ? in[(size_t)i * K + lane] * di * di : 0.0f;
    int beg = row_ptr[i], end = row_ptr[i + 1];
    for (int b = beg; b < end; b += 64) {
        int m = end - b; if (m > 64) m = 64;
        int sidx = 0; float wgt = 0.0f;
        if (lane < m) { sidx = csr_src[b + lane]; wgt = csr_w[b + lane]; }
        for (int t = 0; t < m; ++t) {
            int s = __shfl(sidx, t, 64);
            float ww = __shfl(wgt, t, 64);
            if (lane < K) acc = fmaf(in[(size_t)s * K + lane], ww, acc);
        }
    }
    float y;
    if (HAS_W) {
        y = (lane < M) ? bias[lane] : 0.0f;
#pragma unroll
        for (int k = 0; k < K; ++k) {
            float a = __shfl(acc, k, 64);
            y = fmaf(a, Ws[k * M + (lane & (M - 1))], y);
        }
    } else {
        y = acc + ((lane < M) ? bias[lane] : 0.0f);
    }
    if (RELU) y = fmaxf(y, 0.0f);
    if (lane < M) out[(size_t)i * M + lane] = y;
}

extern "C" void kernel_launch(void* const* d_in, const int* in_sizes, int n_in,
                              void* d_out, int out_size, void* d_ws, size_t ws_size,
                              hipStream_t stream) {
    (void)n_in; (void)out_size; (void)ws_size;

    const float* x  = (const float*)d_in[0];
    const int*   ei = (const int*)d_in[1];
    const float* W1 = (const float*)d_in[2];  const float* b1 = (const float*)d_in[3];
    const float* W2 = (const float*)d_in[4];  const float* b2 = (const float*)d_in[5];
    const float* W3 = (const float*)d_in[6];  const float* b3 = (const float*)d_in[7];
    const float* W4 = (const float*)d_in[8];  const float* b4 = (const float*)d_in[9];
    const float* W5 = (const float*)d_in[10]; const float* b5 = (const float*)d_in[11];
    const float* W6 = (const float*)d_in[12]; const float* b6 = (const float*)d_in[13];

    const int n = in_sizes[0] / 64;   // 100000
    const int E = in_sizes[1] / 2;    // 1600000
    const int* src = ei;
    const int* dst = ei + E;

    float* out  = (float*)d_out;
    float* xrec = out;                       // [n,64]
    float* z    = out + (size_t)n * 64;      // [n,32]

    char* ws = (char*)d_ws;
    size_t off = 0;
    float* dinv    = (float*)(ws + off); off += align256((size_t)n * 4);
    int*   cnt     = (int*)(ws + off);   off += align256((size_t)n * 4);
    int*   row_ptr = (int*)(ws + off);   off += align256((size_t)(n + 1) * 4);
    int*   cur     = (int*)(ws + off);   off += align256((size_t)n * 4);
    int*   csr_src = (int*)(ws + off);   off += align256((size_t)E * 4);
    float* csr_w   = (float*)(ws + off); off += align256((size_t)E * 4);
    float* buf0    = (float*)(ws + off); off += align256((size_t)n * 32 * 4);  // L3 mm scratch
    float* buf1    = (float*)(ws + off); off += align256((size_t)n * 64 * 4);
    float* buf2    = (float*)(ws + off); off += align256((size_t)n * 64 * 4);

    const int B = 256;
    const int nodeGrid = (n + 3) / 4;   // 4 waves per block
    const int edgeGrid = (E + B - 1) / B;

    // ---- CSR build ----
    hipMemsetAsync(cnt, 0, (size_t)n * 4, stream);
    hist_kernel<<<edgeGrid, B, 0, stream>>>(dst, E, cnt);
    dinv_kernel<<<(n + B - 1) / B, B, 0, stream>>>(cnt, dinv, n);
    scan_kernel<<<1, 1024, 0, stream>>>(cnt, row_ptr, n);
    hipMemsetAsync(cur, 0, (size_t)n * 4, stream);
    scatter_kernel<<<edgeGrid, B, 0, stream>>>(src, dst, E, row_ptr, cur, dinv, csr_src, csr_w);

    // ---- Layer 1: (A x) W1 + b1, relu -> buf1 ----
    fused_layer<64, 64, true, true><<<nodeGrid, B, 0, stream>>>(
        x, W1, b1, row_ptr, csr_src, csr_w, dinv, buf1, n);
    // ---- Layer 2 -> buf2 ----
    fused_layer<64, 64, true, true><<<nodeGrid, B, 0, stream>>>(
        buf1, W2, b2, row_ptr, csr_src, csr_w, dinv, buf2, n);
    // ---- Layer 3: mm = buf2 @ W3 (64->32), then A mm + b3 -> z ----
    matmul_kernel<64, 32><<<nodeGrid, B, 0, stream>>>(buf2, W3, buf0, n);
    fused_layer<32, 32, false, false><<<nodeGrid, B, 0, stream>>>(
        buf0, nullptr, b3, row_ptr, csr_src, csr_w, dinv, z, n);
    // ---- Layer 4: (A z) W4 + b4, relu -> buf1  (aggregate at 32 wide) ----
    fused_layer<32, 64, true, true><<<nodeGrid, B, 0, stream>>>(
        z, W4, b4, row_ptr, csr_src, csr_w, dinv, buf1, n);
    // ---- Layer 5 -> buf2 ----
    fused_layer<64, 64, true, true><<<nodeGrid, B, 0, stream>>>(
        buf1, W5, b5, row_ptr, csr_src, csr_w, dinv, buf2, n);
    // ---- Layer 6 (no relu) -> xrec ----
    fused_layer<64, 64, false, true><<<nodeGrid, B, 0, stream>>>(
        buf2, W6, b6, row_ptr, csr_src, csr_w, dinv, xrec, n);
}

// Round 3
// 1150.699 us; speedup vs baseline: 2.4017x; 1.2362x over previous
//
#include <hip/hip_runtime.h>

// GCN autoencoder, fp32, CSR gather-based.
// R2: quarter-wave float4 gathers — each K-float row is read by K/4 lanes x float4,
// so one wave-load covers 64/(K/4) edges. Interleaved CSR records (int2: src, w).

static inline size_t align256(size_t x) { return (x + 255) & ~(size_t)255; }

__global__ void hist_kernel(const int* __restrict__ dst, int E, int* __restrict__ cnt) {
    int e = blockIdx.x * blockDim.x + threadIdx.x;
    if (e < E) atomicAdd(&cnt[dst[e]], 1);
}

__global__ void dinv_kernel(const int* __restrict__ cnt, float* __restrict__ dinv, int n) {
    int i = blockIdx.x * blockDim.x + threadIdx.x;
    if (i < n) dinv[i] = rsqrtf((float)cnt[i] + 1.0f);  // +1 self loop
}

// Single-block exclusive scan: row_ptr[0]=0, row_ptr[i+1]=sum(cnt[0..i]).
__global__ void scan_kernel(const int* __restrict__ cnt, int* __restrict__ row_ptr, int n) {
    __shared__ int wsum[16];
    __shared__ int carry;
    int tid = threadIdx.x, lane = tid & 63, wv = tid >> 6;
    if (tid == 0) { carry = 0; row_ptr[0] = 0; }
    __syncthreads();
    for (int base = 0; base < n; base += 1024) {
        int idx = base + tid;
        int v = (idx < n) ? cnt[idx] : 0;
        int x = v;
#pragma unroll
        for (int off = 1; off < 64; off <<= 1) {
            int t = __shfl_up(x, off, 64);
            if (lane >= off) x += t;
        }
        if (lane == 63) wsum[wv] = x;
        __syncthreads();
        if (wv == 0 && lane < 16) {
            int s = wsum[lane];
#pragma unroll
            for (int off = 1; off < 16; off <<= 1) {
                int t = __shfl_up(s, off, 16);
                if ((lane & 15) >= off) s += t;
            }
            wsum[lane] = s;
        }
        __syncthreads();
        int waveoff = (wv == 0) ? 0 : wsum[wv - 1];
        if (idx < n) row_ptr[idx + 1] = carry + waveoff + x;
        __syncthreads();
        if (tid == 0) carry += wsum[15];
        __syncthreads();
    }
}

__global__ void scatter_kernel(const int* __restrict__ src, const int* __restrict__ dst, int E,
                               const int* __restrict__ row_ptr, int* __restrict__ cur,
                               const float* __restrict__ dinv,
                               int2* __restrict__ csr) {
    int e = blockIdx.x * blockDim.x + threadIdx.x;
    if (e >= E) return;
    int s = src[e], d = dst[e];
    int pos = row_ptr[d] + atomicAdd(&cur[d], 1);
    csr[pos] = make_int2(s, __float_as_int(dinv[s] * dinv[d]));
}

// Wave-per-node matmul (layer 3 pre-agg shrink 64->32).
template <int K, int M>
__global__ void matmul_kernel(const float* __restrict__ in, const float* __restrict__ W,
                              float* __restrict__ out, int n) {
    __shared__ float Ws[K * M];
    for (int t = threadIdx.x; t < K * M; t += blockDim.x) Ws[t] = W[t];
    __syncthreads();
    int wave = threadIdx.x >> 6, lane = threadIdx.x & 63;
    int node = blockIdx.x * (blockDim.x >> 6) + wave;
    if (node >= n) return;
    float x = (lane < K) ? in[(size_t)node * K + lane] : 0.0f;
    int j = lane & (M - 1);
    float acc = 0.0f;
#pragma unroll
    for (int k = 0; k < K; ++k) acc = fmaf(__shfl(x, k, 64), Ws[k * M + j], acc);
    if (lane < M) out[(size_t)node * M + lane] = acc;
}

// Fused: aggregate (self + CSR neighbors) at width K via quarter-wave float4 gathers,
// then optional @W (K->M) + bias + optional relu.
// Lane layout: g = lane/LPR (edge slot), sub = lane%LPR (float4 column within row).
template <int K, int M, bool RELU, bool HAS_W>
__global__ void __launch_bounds__(256) fused_layer(
        const float* __restrict__ in, const float* __restrict__ W,
        const float* __restrict__ bias,
        const int* __restrict__ row_ptr, const int2* __restrict__ csr,
        const float* __restrict__ dinv,
        float* __restrict__ out, int n) {
    constexpr int LPR = K / 4;     // lanes per row
    constexpr int EPW = 64 / LPR;  // edges per wave-iteration
    __shared__ float Ws[HAS_W ? K * M : 1];
    if (HAS_W) {
        for (int t = threadIdx.x; t < K * M; t += blockDim.x) Ws[t] = W[t];
        __syncthreads();
    }
    int wave = threadIdx.x >> 6, lane = threadIdx.x & 63;
    int i = blockIdx.x * (blockDim.x >> 6) + wave;
    if (i >= n) return;
    int g = lane / LPR, sub = lane % LPR;

    float4 acc = make_float4(0.f, 0.f, 0.f, 0.f);
    // self-loop term (group 0 only; cross-group reduction sums it once)
    if (g == 0) {
        float di = dinv[i];
        float w2 = di * di;
        float4 v = ((const float4*)(in + (size_t)i * K))[sub];
        acc.x = w2 * v.x; acc.y = w2 * v.y; acc.z = w2 * v.z; acc.w = w2 * v.w;
    }

    int beg = row_ptr[i], end = row_ptr[i + 1];
    for (int b = beg; b < end; b += 64) {
        int m = end - b; if (m > 64) m = 64;
        int sidx = 0; float wgt = 0.0f;
        if (lane < m) {
            int2 r = csr[b + lane];
            sidx = r.x; wgt = __int_as_float(r.y);
        }
        int iters = (m + EPW - 1) / EPW;
        for (int t = 0; t < iters; ++t) {
            int el = t * EPW + g;            // edge slot for this lane-group
            int s = __shfl(sidx, el, 64);
            float ww = __shfl(wgt, el, 64);  // 0 for padded slots
            float4 v = ((const float4*)(in + (size_t)s * K))[sub];
            acc.x = fmaf(ww, v.x, acc.x);
            acc.y = fmaf(ww, v.y, acc.y);
            acc.z = fmaf(ww, v.z, acc.z);
            acc.w = fmaf(ww, v.w, acc.w);
        }
    }

    // reduce partial sums across edge-groups (lanes with equal sub)
#pragma unroll
    for (int off = LPR; off < 64; off <<= 1) {
        acc.x += __shfl_xor(acc.x, off, 64);
        acc.y += __shfl_xor(acc.y, off, 64);
        acc.z += __shfl_xor(acc.z, off, 64);
        acc.w += __shfl_xor(acc.w, off, 64);
    }

    if (HAS_W) {
        // every lane j computes out[i][j] = sum_k a_k W[k][j] + b[j]
        int j = lane & (M - 1);
        float y = (lane < M) ? bias[j] : 0.0f;
#pragma unroll
        for (int s = 0; s < LPR; ++s) {
            float ax = __shfl(acc.x, s, 64);
            float ay = __shfl(acc.y, s, 64);
            float az = __shfl(acc.z, s, 64);
            float aw = __shfl(acc.w, s, 64);
            y = fmaf(ax, Ws[(4 * s + 0) * M + j], y);
            y = fmaf(ay, Ws[(4 * s + 1) * M + j], y);
            y = fmaf(az, Ws[(4 * s + 2) * M + j], y);
            y = fmaf(aw, Ws[(4 * s + 3) * M + j], y);
        }
        if (RELU) y = fmaxf(y, 0.0f);
        if (lane < M) out[(size_t)i * M + lane] = y;
    } else {
        // K == M: group 0 stores its float4 directly
        if (g == 0) {
            float4 bb = ((const float4*)bias)[sub];
            float4 y = make_float4(acc.x + bb.x, acc.y + bb.y, acc.z + bb.z, acc.w + bb.w);
            if (RELU) {
                y.x = fmaxf(y.x, 0.f); y.y = fmaxf(y.y, 0.f);
                y.z = fmaxf(y.z, 0.f); y.w = fmaxf(y.w, 0.f);
            }
            ((float4*)(out + (size_t)i * M))[sub] = y;
        }
    }
}

extern "C" void kernel_launch(void* const* d_in, const int* in_sizes, int n_in,
                              void* d_out, int out_size, void* d_ws, size_t ws_size,
                              hipStream_t stream) {
    (void)n_in; (void)out_size; (void)ws_size;

    const float* x  = (const float*)d_in[0];
    const int*   ei = (const int*)d_in[1];
    const float* W1 = (const float*)d_in[2];  const float* b1 = (const float*)d_in[3];
    const float* W2 = (const float*)d_in[4];  const float* b2 = (const float*)d_in[5];
    const float* W3 = (const float*)d_in[6];  const float* b3 = (const float*)d_in[7];
    const float* W4 = (const float*)d_in[8];  const float* b4 = (const float*)d_in[9];
    const float* W5 = (const float*)d_in[10]; const float* b5 = (const float*)d_in[11];
    const float* W6 = (const float*)d_in[12]; const float* b6 = (const float*)d_in[13];

    const int n = in_sizes[0] / 64;   // 100000
    const int E = in_sizes[1] / 2;    // 1600000
    const int* src = ei;
    const int* dst = ei + E;

    float* out  = (float*)d_out;
    float* xrec = out;                       // [n,64]
    float* z    = out + (size_t)n * 64;      // [n,32]

    char* ws = (char*)d_ws;
    size_t off = 0;
    float* dinv    = (float*)(ws + off); off += align256((size_t)n * 4);
    int*   cnt     = (int*)(ws + off);   off += align256((size_t)n * 4);
    int*   row_ptr = (int*)(ws + off);   off += align256((size_t)(n + 1) * 4);
    int*   cur     = (int*)(ws + off);   off += align256((size_t)n * 4);
    int2*  csr     = (int2*)(ws + off);  off += align256((size_t)E * 8);
    float* buf0    = (float*)(ws + off); off += align256((size_t)n * 32 * 4);  // L3 mm scratch
    float* buf1    = (float*)(ws + off); off += align256((size_t)n * 64 * 4);
    float* buf2    = (float*)(ws + off); off += align256((size_t)n * 64 * 4);

    const int B = 256;
    const int nodeGrid = (n + 3) / 4;   // 4 waves (nodes) per block
    const int edgeGrid = (E + B - 1) / B;

    // ---- CSR build ----
    hipMemsetAsync(cnt, 0, (size_t)n * 4, stream);
    hist_kernel<<<edgeGrid, B, 0, stream>>>(dst, E, cnt);
    dinv_kernel<<<(n + B - 1) / B, B, 0, stream>>>(cnt, dinv, n);
    scan_kernel<<<1, 1024, 0, stream>>>(cnt, row_ptr, n);
    hipMemsetAsync(cur, 0, (size_t)n * 4, stream);
    scatter_kernel<<<edgeGrid, B, 0, stream>>>(src, dst, E, row_ptr, cur, dinv, csr);

    // ---- Layer 1: (A x) W1 + b1, relu -> buf1 ----
    fused_layer<64, 64, true, true><<<nodeGrid, B, 0, stream>>>(
        x, W1, b1, row_ptr, csr, dinv, buf1, n);
    // ---- Layer 2 -> buf2 ----
    fused_layer<64, 64, true, true><<<nodeGrid, B, 0, stream>>>(
        buf1, W2, b2, row_ptr, csr, dinv, buf2, n);
    // ---- Layer 3: mm = buf2 @ W3 (64->32), then A mm + b3 -> z ----
    matmul_kernel<64, 32><<<nodeGrid, B, 0, stream>>>(buf2, W3, buf0, n);
    fused_layer<32, 32, false, false><<<nodeGrid, B, 0, stream>>>(
        buf0, nullptr, b3, row_ptr, csr, dinv, z, n);
    // ---- Layer 4: (A z) W4 + b4, relu -> buf1  (aggregate at 32 wide) ----
    fused_layer<32, 64, true, true><<<nodeGrid, B, 0, stream>>>(
        z, W4, b4, row_ptr, csr, dinv, buf1, n);
    // ---- Layer 5 -> buf2 ----
    fused_layer<64, 64, true, true><<<nodeGrid, B, 0, stream>>>(
        buf1, W5, b5, row_ptr, csr, dinv, buf2, n);
    // ---- Layer 6 (no relu) -> xrec ----
    fused_layer<64, 64, false, true><<<nodeGrid, B, 0, stream>>>(
        buf2, W6, b6, row_ptr, csr, dinv, xrec, n);
}